// Round 7
// baseline (223.721 us; speedup 1.0000x reference)
//
#include <hip/hip_runtime.h>
#include <hip/hip_bf16.h>

#define B_  2
#define S_  2048
#define D_  1024
#define H_  16
#define HD_ 64

typedef __attribute__((ext_vector_type(4))) short s16x4;
typedef __attribute__((ext_vector_type(8))) short s16x8;
typedef __attribute__((ext_vector_type(4))) float f32x4;
typedef __attribute__((ext_vector_type(8))) __bf16 bf16x8;

__device__ __forceinline__ unsigned short f2bf(float x) {
  union { float f; unsigned int u; } un; un.f = x;
  unsigned int r = un.u + 0x7fffu + ((un.u >> 16) & 1u);  // RNE
  return (unsigned short)(r >> 16);
}

// v_cvt_pk_bf16_f32: dst.lo = bf16(lo), dst.hi = bf16(hi)  (no builtin on gfx950)
__device__ __forceinline__ unsigned cvtpk(float lo, float hi) {
  unsigned r;
  asm("v_cvt_pk_bf16_f32 %0, %1, %2" : "=v"(r) : "v"(lo), "v"(hi));
  return r;
}

// raw v_exp_f32: 2^x
__device__ __forceinline__ float exp2a(float x) {
  float r;
  asm("v_exp_f32 %0, %1" : "=v"(r) : "v"(x));
  return r;
}

__device__ __forceinline__ f32x4 fz4() { f32x4 z = {0.f, 0.f, 0.f, 0.f}; return z; }

__device__ __forceinline__ f32x4 mfma32(s16x8 a, s16x8 b, f32x4 c) {
  return __builtin_amdgcn_mfma_f32_16x16x32_bf16(
      __builtin_bit_cast(bf16x8, a), __builtin_bit_cast(bf16x8, b), c, 0, 0, 0);
}

// async global->LDS, 16B per lane. Dest is wave-uniform base + lane*16 (HW adds lane).
__device__ __forceinline__ void gload16(void* lds_base, const void* gsrc) {
  __builtin_amdgcn_global_load_lds(
      (const __attribute__((address_space(1))) unsigned int*)gsrc,
      (__attribute__((address_space(3))) unsigned int*)lds_base, 16, 0, 0);
}

// ---------------- fp32 -> bf16 convert, ALL 7 tensors in one launch ----------------
__global__ __launch_bounds__(256) void cvt_all(const float4* __restrict__ q,
                                               const float4* __restrict__ k,
                                               const float4* __restrict__ v,
                                               const float4* __restrict__ wq,
                                               const float4* __restrict__ wk,
                                               const float4* __restrict__ wv,
                                               const float4* __restrict__ wo,
                                               uint2* __restrict__ oq, uint2* __restrict__ ok,
                                               uint2* __restrict__ ov, uint2* __restrict__ owq,
                                               uint2* __restrict__ owk, uint2* __restrict__ owv,
                                               uint2* __restrict__ owo) {
  int i = blockIdx.x * 256 + threadIdx.x;
  int st = gridDim.x * 256;
  for (; i < 4194304; i += st) {
    const float4* s; uint2* d; int off;
    if (i < 3145728) {
      int t = i >> 20; off = i & 1048575;
      s = (t == 0) ? q : (t == 1 ? k : v);
      d = (t == 0) ? oq : (t == 1 ? ok : ov);
    } else {
      int j = i - 3145728;
      int t = j >> 18; off = j & 262143;
      s = (t == 0) ? wq : (t == 1 ? wk : (t == 2 ? wv : wo));
      d = (t == 0) ? owq : (t == 1 ? owk : (t == 2 ? owv : owo));
    }
    float4 x = s[off];
    uint2 o;
    o.x = cvtpk(x.x, x.y);
    o.y = cvtpk(x.z, x.w);
    d[off] = o;
  }
}

// ---------------- QKV GEMM, m97 structure: 128x128 tile, BK=64, single-buffered LDS,
//   global_load_lds staging (source-side chunk swizzle), 768 blocks = 3/CU resident.
__global__ __launch_bounds__(256) void qkv_gemm(
    const unsigned short* __restrict__ A0, const unsigned short* __restrict__ A1,
    const unsigned short* __restrict__ A2,
    const unsigned short* __restrict__ W0, const unsigned short* __restrict__ W1,
    const unsigned short* __restrict__ W2,
    unsigned short* __restrict__ ob0, unsigned short* __restrict__ ob1,
    unsigned short* __restrict__ ob2) {
  __shared__ unsigned short As[128 * 64];   // linear dest, content chunk-swizzled
  __shared__ unsigned short Bs[128 * 64];
  const int tid  = threadIdx.x;
  const int lane = tid & 63;
  const int w    = tid >> 6;
  const int l15  = lane & 15, g = lane >> 4;

  // 768 blocks = 8 XCDs x 96; 96 consecutive = 3 N-panels (W L2-resident per XCD)
  int swz = ((int)blockIdx.x & 7) * 96 + ((int)blockIdx.x >> 3);
  const int p  = swz >> 5;          // panel 0..23
  const int gi = p >> 3;            // which projection
  const int n0 = (p & 7) * 128;
  const int m0 = (swz & 31) * 128;
  const unsigned short* A = gi == 0 ? A0 : (gi == 1 ? A1 : A2);
  const unsigned short* W = gi == 0 ? W0 : (gi == 1 ? W1 : W2);
  unsigned short* obf     = gi == 0 ? ob0 : (gi == 1 ? ob1 : ob2);
  // fold 1/sqrt(HD) * log2(e) into Q so attention softmax runs in exp2 domain
  const float scale = (gi == 0) ? 0.125f * 1.44269504f : 1.0f;

  const int wr = (w >> 1) * 64, wc = (w & 1) * 64;

  f32x4 acc[4][4];
  #pragma unroll
  for (int i = 0; i < 4; i++)
    #pragma unroll
    for (int j = 0; j < 4; j++) acc[i][j] = fz4();

  const int srow = tid >> 3;                                 // 0..31 (+ i*32)
  const int scol = ((lane & 7) ^ ((lane >> 3) & 7)) * 8;     // pre-swizzled source chunk

  for (int k0 = 0; k0 < D_; k0 += 64) {
    #pragma unroll
    for (int i = 0; i < 4; i++) {
      gload16(&As[(i * 256 + w * 64) * 8], &A[(size_t)(m0 + i * 32 + srow) * D_ + k0 + scol]);
      gload16(&Bs[(i * 256 + w * 64) * 8], &W[(size_t)(n0 + i * 32 + srow) * D_ + k0 + scol]);
    }
    __syncthreads();
    #pragma unroll
    for (int kk = 0; kk < 2; kk++) {
      s16x8 af[4], bfr[4];
      #pragma unroll
      for (int mi = 0; mi < 4; mi++)
        af[mi] = *(const s16x8*)&As[(wr + mi * 16 + l15) * 64 + (((kk * 4 + g) ^ (l15 & 7)) * 8)];
      #pragma unroll
      for (int ni = 0; ni < 4; ni++)
        bfr[ni] = *(const s16x8*)&Bs[(wc + ni * 16 + l15) * 64 + (((kk * 4 + g) ^ (l15 & 7)) * 8)];
      #pragma unroll
      for (int mi = 0; mi < 4; mi++)
        #pragma unroll
        for (int ni = 0; ni < 4; ni++)
          acc[mi][ni] = mfma32(af[mi], bfr[ni], acc[mi][ni]);
    }
    __syncthreads();
  }

  #pragma unroll
  for (int mi = 0; mi < 4; mi++)
    #pragma unroll
    for (int ni = 0; ni < 4; ni++)
      #pragma unroll
      for (int j = 0; j < 4; j++) {
        int r = m0 + wr + mi * 16 + 4 * g + j;   // output row (b*S+s)
        int c = n0 + wc + ni * 16 + l15;         // output col (h*HD+hd)
        float v = acc[mi][ni][j] * scale;
        int b = r >> 11, s = r & (S_ - 1), h = c >> 6, hd = c & 63;
        obf[(((size_t)(b * H_ + h)) * S_ + s) * HD_ + hd] = f2bf(v);
      }
}

// ---------------- Wo GEMM, m97 structure at 64x128: BK=64, single-buffered,
//   512 blocks = 2/CU resident, fp32 row-major out.
__global__ __launch_bounds__(256) void gemm_wo(const unsigned short* __restrict__ A,
                                               const unsigned short* __restrict__ W,
                                               float* __restrict__ of) {
  __shared__ unsigned short As[64 * 64];
  __shared__ unsigned short Bs[128 * 64];
  const int tid  = threadIdx.x;
  const int lane = tid & 63;
  const int w    = tid >> 6;
  const int l15  = lane & 15, g = lane >> 4;

  int swz = ((int)blockIdx.x & 7) * 64 + ((int)blockIdx.x >> 3);
  const int m0 = (swz & 63) * 64;
  const int n0 = (swz >> 6) * 128;
  const int wr = (w >> 1) * 32, wc = (w & 1) * 64;

  f32x4 acc[2][4];
  #pragma unroll
  for (int i = 0; i < 2; i++)
    #pragma unroll
    for (int j = 0; j < 4; j++) acc[i][j] = fz4();

  const int srow = tid >> 3;                                 // 0..31 (+ i*32)
  const int scol = ((lane & 7) ^ ((lane >> 3) & 7)) * 8;

  for (int k0 = 0; k0 < D_; k0 += 64) {
    #pragma unroll
    for (int i = 0; i < 2; i++)
      gload16(&As[(i * 256 + w * 64) * 8], &A[(size_t)(m0 + i * 32 + srow) * D_ + k0 + scol]);
    #pragma unroll
    for (int i = 0; i < 4; i++)
      gload16(&Bs[(i * 256 + w * 64) * 8], &W[(size_t)(n0 + i * 32 + srow) * D_ + k0 + scol]);
    __syncthreads();
    #pragma unroll
    for (int kk = 0; kk < 2; kk++) {
      s16x8 af[2], bfr[4];
      #pragma unroll
      for (int mi = 0; mi < 2; mi++)
        af[mi] = *(const s16x8*)&As[(wr + mi * 16 + l15) * 64 + (((kk * 4 + g) ^ (l15 & 7)) * 8)];
      #pragma unroll
      for (int ni = 0; ni < 4; ni++)
        bfr[ni] = *(const s16x8*)&Bs[(wc + ni * 16 + l15) * 64 + (((kk * 4 + g) ^ (l15 & 7)) * 8)];
      #pragma unroll
      for (int mi = 0; mi < 2; mi++)
        #pragma unroll
        for (int ni = 0; ni < 4; ni++)
          acc[mi][ni] = mfma32(af[mi], bfr[ni], acc[mi][ni]);
    }
    __syncthreads();
  }

  #pragma unroll
  for (int mi = 0; mi < 2; mi++)
    #pragma unroll
    for (int ni = 0; ni < 4; ni++)
      #pragma unroll
      for (int j = 0; j < 4; j++) {
        int r = m0 + wr + mi * 16 + 4 * g + j;
        int c = n0 + wc + ni * 16 + l15;
        of[(size_t)r * D_ + c] = acc[mi][ni][j];
      }
}

// ---------------- Fused causal attention, quiet softmax (+1), PRE-MASK full-row max.
//   8 waves / 512 threads; paired q-tiles {i, 31-i} share K/V LDS (perfect balance).
//   Swapped QK^T; PV flipped (out^T = V^T P^T) -> lane-local stats. Scores arrive
//   pre-scaled by log2(e)/8, so softmax uses raw v_exp_f32 (2^x) and
//   v_cvt_pk_bf16_f32 packing (VALU cut ~2x vs f2bf path).
__global__ __launch_bounds__(512) void attn_kernel(const unsigned short* __restrict__ Qh,
                                                   const unsigned short* __restrict__ Kh,
                                                   const unsigned short* __restrict__ Vh,
                                                   unsigned short* __restrict__ AO) {
  __shared__ unsigned short Ks[2][64 * 64];   // [key][64] linear, chunk-swizzled content
  __shared__ unsigned short Vt[2][64 * 76];   // [hd][key], pad 76: conflict-free
  const int tid  = threadIdx.x;
  const int lane = tid & 63;
  const int w    = tid >> 6;       // 0..7
  const int wq   = w & 3;          // wave-in-group
  const int grp  = w >> 2;         // 0: tile A, 1: tile B
  const int l15  = lane & 15, g = lane >> 4;

  int swz = ((int)blockIdx.x & 7) * 64 + ((int)blockIdx.x >> 3);  // 512 blocks
  const int bh = swz >> 4;         // b*H + h
  const int pr = swz & 15;         // pair index
  const int qtA = pr, qtB = 31 - pr;
  const int myqt  = grp ? qtB : qtA;
  const int qtMax = qtB;           // qtB >= 16 > qtA
  const int q0 = myqt * 64;
  const unsigned short* Qb = Qh + (size_t)bh * S_ * HD_;
  const unsigned short* Kb = Kh + (size_t)bh * S_ * HD_;
  const unsigned short* Vb = Vh + (size_t)bh * S_ * HD_;

  const int qrow = q0 + wq * 16 + l15;  // this lane's q (column of S^T and of out^T)
  s16x8 qf[2];
  #pragma unroll
  for (int kk = 0; kk < 2; kk++)
    qf[kk] = *(const s16x8*)&Qb[(size_t)qrow * HD_ + kk * 32 + 8 * g];

  float m = -INFINITY, l = 0.f;     // stats (exp2 domain) for q = l15-row: lane-local
  f32x4 outa[4];                    // out^T: col=l15=q, rows 4g+j = hd within d*16
  #pragma unroll
  for (int d = 0; d < 4; d++) outa[d] = fz4();

  const int srow_l = lane >> 3;
  const int scol = ((lane & 7) ^ ((lane >> 3) & 7)) * 8;
  const int vkey = tid & 63;
  const int vhd0 = (tid >> 6) * 8;

  #define STAGE_K(kblk, b)                                                        \
    gload16(&Ks[b][(w * 8) * 64],                                                 \
            &Kb[(size_t)((kblk) * 64 + w * 8 + srow_l) * HD_ + scol]);
  #define LOAD_V(kblk, vr)                                                        \
    vr = *(const uint4*)&Vb[(size_t)((kblk) * 64 + vkey) * HD_ + vhd0];
  #define WRITE_V(b, vr)                                                          \
    {                                                                             \
      unsigned int u[4] = {vr.x, vr.y, vr.z, vr.w};                               \
      _Pragma("unroll")                                                           \
      for (int c2 = 0; c2 < 4; c2++) {                                            \
        Vt[b][(vhd0 + 2 * c2    ) * 76 + vkey] = (unsigned short)(u[c2] & 0xffffu); \
        Vt[b][(vhd0 + 2 * c2 + 1) * 76 + vkey] = (unsigned short)(u[c2] >> 16);   \
      }                                                                           \
    }

  { // prologue: stage block 0 (V block 0 always causal)
    STAGE_K(0, 0);
    uint4 vr0;
    LOAD_V(0, vr0);
    WRITE_V(0, vr0);
    __syncthreads();
  }

  for (int t = 0; t < 32; ++t) {
    const int cur = t & 1, nxt = cur ^ 1;
    const int k0 = t * 64;
    if (t < 31) STAGE_K(t + 1, nxt);
    uint4 vr;
    const bool vnext = (t < 31) && (t + 1 <= qtMax);
    if (vnext) LOAD_V(t + 1, vr);

    // S^T(64key x 16q) per wave  (values already in exp2 domain)
    f32x4 sf[4];
    #pragma unroll
    for (int kt = 0; kt < 4; kt++) sf[kt] = fz4();
    __builtin_amdgcn_s_setprio(1);
    #pragma unroll
    for (int kt = 0; kt < 4; kt++)
      #pragma unroll
      for (int kk = 0; kk < 2; kk++) {
        s16x8 kf = *(const s16x8*)&Ks[cur][(kt * 16 + l15) * 64 + (((kk * 4 + g) ^ (l15 & 7)) * 8)];
        sf[kt] = mfma32(kf, qf[kk], sf[kt]);
      }
    __builtin_amdgcn_s_setprio(0);

    // pre-mask block max for this lane's q, then across the 4 lane-groups
    float bm = fmaxf(fmaxf(fmaxf(sf[0][0], sf[0][1]), fmaxf(sf[0][2], sf[0][3])),
                     fmaxf(fmaxf(sf[1][0], sf[1][1]), fmaxf(sf[1][2], sf[1][3])));
    float bm2 = fmaxf(fmaxf(fmaxf(sf[2][0], sf[2][1]), fmaxf(sf[2][2], sf[2][3])),
                      fmaxf(fmaxf(sf[3][0], sf[3][1]), fmaxf(sf[3][2], sf[3][3])));
    bm = fmaxf(bm, bm2);
    bm = fmaxf(bm, __shfl_xor(bm, 16));
    bm = fmaxf(bm, __shfl_xor(bm, 32));
    if (__any(bm > m)) {            // exact defer-max; lane-local rescale
      float mn  = fmaxf(m, bm);
      float fsc = exp2a(m - mn);    // m = -inf initially -> 0
      m = mn;
      l *= fsc;
      #pragma unroll
      for (int d = 0; d < 4; d++)
        #pragma unroll
        for (int j = 0; j < 4; j++) outa[d][j] *= fsc;
    }

    if (t <= myqt) {
      s16x8 pfs[2];
      float rs = 0.f;
      #pragma unroll
      for (int kt2 = 0; kt2 < 2; kt2++) {
        float eA[4], eB[4];
        if (t == myqt) {   // diagonal block: causal select per element
          #pragma unroll
          for (int j = 0; j < 4; j++) {
            int keyg = k0 + kt2 * 32 + 4 * g + j;
            float xA = exp2a(sf[2 * kt2][j] - m);
            float xB = exp2a(sf[2 * kt2 + 1][j] - m);
            eA[j] = (keyg <= qrow) ? xA : 0.f;
            eB[j] = (keyg + 16 <= qrow) ? xB : 0.f;
          }
        } else {           // strictly-below blocks: no mask
          #pragma unroll
          for (int j = 0; j < 4; j++) {
            eA[j] = exp2a(sf[2 * kt2][j] - m);
            eB[j] = exp2a(sf[2 * kt2 + 1][j] - m);
          }
        }
        uint4 pw;
        pw.x = cvtpk(eA[0], eA[1]);
        pw.y = cvtpk(eA[2], eA[3]);
        pw.z = cvtpk(eB[0], eB[1]);
        pw.w = cvtpk(eB[2], eB[3]);
        pfs[kt2] = __builtin_bit_cast(s16x8, pw);
        rs += ((eA[0] + eA[1]) + (eA[2] + eA[3])) + ((eB[0] + eB[1]) + (eB[2] + eB[3]));
      }
      rs += __shfl_xor(rs, 16);
      rs += __shfl_xor(rs, 32);
      l += rs;
      __builtin_amdgcn_s_setprio(1);
      #pragma unroll
      for (int d = 0; d < 4; d++)
        #pragma unroll
        for (int kt2 = 0; kt2 < 2; kt2++) {
          s16x4 vlo = *(const s16x4*)&Vt[cur][(d * 16 + l15) * 76 + kt2 * 32 + 4 * g];
          s16x4 vhi = *(const s16x4*)&Vt[cur][(d * 16 + l15) * 76 + kt2 * 32 + 16 + 4 * g];
          s16x8 vv = {vlo[0], vlo[1], vlo[2], vlo[3], vhi[0], vhi[1], vhi[2], vhi[3]};
          outa[d] = mfma32(vv, pfs[kt2], outa[d]);   // out^T += V^T * P^T
        }
      __builtin_amdgcn_s_setprio(0);
    }

    if (vnext) WRITE_V(nxt, vr);   // write-late: V regs land after compute
    __syncthreads();
  }
  #undef STAGE_K
  #undef LOAD_V
  #undef WRITE_V

  const float inv = 1.f / (l + 1.f);   // quiet softmax +1; lane-local
  const int b = bh >> 4, h = bh & 15;
  #pragma unroll
  for (int d = 0; d < 4; d++) {
    uint2 o;
    o.x = cvtpk(outa[d][0] * inv, outa[d][1] * inv);
    o.y = cvtpk(outa[d][2] * inv, outa[d][3] * inv);
    *(uint2*)&AO[(size_t)(b * S_ + qrow) * D_ + h * 64 + d * 16 + 4 * g] = o;
  }
}

extern "C" void kernel_launch(void* const* d_in, const int* in_sizes, int n_in,
                              void* d_out, int out_size, void* d_ws, size_t ws_size,
                              hipStream_t stream) {
  const float* q  = (const float*)d_in[0];
  const float* k  = (const float*)d_in[1];
  const float* v  = (const float*)d_in[2];
  const float* Wq = (const float*)d_in[3];
  const float* Wk = (const float*)d_in[4];
  const float* Wv = (const float*)d_in[5];
  const float* Wo = (const float*)d_in[6];

  unsigned short* ws  = (unsigned short*)d_ws;
  unsigned short* qb  = ws;                    // 4096x1024 bf16
  unsigned short* kb  = qb  + 4194304;
  unsigned short* vb  = kb  + 4194304;
  unsigned short* Wqb = vb  + 4194304;         // 1024x1024 bf16 x4
  unsigned short* Wkb = Wqb + 1048576;
  unsigned short* Wvb = Wkb + 1048576;
  unsigned short* Wob = Wvb + 1048576;
  unsigned short* Qh  = Wob + 1048576;         // (b,h,s,hd) bf16 x3
  unsigned short* Kh  = Qh  + 4194304;
  unsigned short* Vh  = Kh  + 4194304;
  unsigned short* AO  = Vh  + 4194304;         // attn out, (b*s, h*hd) bf16

  cvt_all<<<2048, 256, 0, stream>>>((const float4*)q, (const float4*)k, (const float4*)v,
                                    (const float4*)Wq, (const float4*)Wk, (const float4*)Wv,
                                    (const float4*)Wo,
                                    (uint2*)qb, (uint2*)kb, (uint2*)vb, (uint2*)Wqb,
                                    (uint2*)Wkb, (uint2*)Wvb, (uint2*)Wob);

  // fused QKV projections: m97 structure, 768 blocks = 3/CU resident
  qkv_gemm<<<768, 256, 0, stream>>>(qb, kb, vb, Wqb, Wkb, Wvb, Qh, Kh, Vh);

  // paired q-tiles: 32 bh x 16 pairs = 512 blocks x 512 threads
  attn_kernel<<<512, 512, 0, stream>>>(Qh, Kh, Vh, AO);

  // output projection: 64x128 tiles, BK=64 single-buffer, 512 blocks (2/CU)
  gemm_wo<<<512, 256, 0, stream>>>(AO, Wob, (float*)d_out);
}